// Round 2
// baseline (87.465 us; speedup 1.0000x reference)
//
#include <hip/hip_runtime.h>
#include <math.h>

#define D     1024
#define D4    256     // D/4
#define BI    48
#define BC    48
#define RR    36
#define TT    40
#define EPSF  1e-5f
#define PRG   40      // cap-stat row groups
#define CROWS 48      // rows per cap-stat group (PRG*CROWS = 1920)
#define NBLK2 60      // cap-normalize blocks
#define ROWS2 32      // rows per normalize block (NBLK2*ROWS2 = 1920)

// ---- K1: cap BN partial sums (blocks 0..39) + img_q/img_n (blocks 40..87)
__global__ __launch_bounds__(256) void k_stats(const float* __restrict__ cap,
                                               const float* __restrict__ img,
                                               float* __restrict__ ps,
                                               float* __restrict__ pss,
                                               float* __restrict__ img_q,
                                               float* __restrict__ img_n) {
    int bx = blockIdx.x, tid = threadIdx.x;
    __shared__ float sw[4];
    if (bx < PRG) {
        const float4* cap4 = (const float4*)cap;
        float4 s = {0,0,0,0}, ss = {0,0,0,0};
        int r0 = bx * CROWS;
#pragma unroll 8
        for (int r = 0; r < CROWS; ++r) {
            float4 v = cap4[(size_t)(r0 + r) * D4 + tid];
            s.x += v.x; s.y += v.y; s.z += v.z; s.w += v.w;
            ss.x += v.x*v.x; ss.y += v.y*v.y; ss.z += v.z*v.z; ss.w += v.w*v.w;
        }
        ((float4*)ps)[(size_t)bx * D4 + tid]  = s;
        ((float4*)pss)[(size_t)bx * D4 + tid] = ss;
    } else {
        int i = bx - PRG;
        const float4* img4 = (const float4*)img;
        float4 s = {0,0,0,0};
#pragma unroll 6
        for (int r = 0; r < RR; ++r) {
            float4 v = img4[((size_t)i * RR + r) * D4 + tid];
            s.x += v.x; s.y += v.y; s.z += v.z; s.w += v.w;
        }
        const float inv = 1.f / 36.f;
        float4 q = {s.x*inv, s.y*inv, s.z*inv, s.w*inv};
        ((float4*)img_q)[(size_t)i * D4 + tid] = q;
        float ssq = q.x*q.x + q.y*q.y + q.z*q.z + q.w*q.w;
#pragma unroll
        for (int off = 32; off; off >>= 1) ssq += __shfl_xor(ssq, off, 64);
        if ((tid & 63) == 0) sw[tid >> 6] = ssq;
        __syncthreads();
        float rinv = rsqrtf(sw[0] + sw[1] + sw[2] + sw[3]);
        float4 n = {q.x*rinv, q.y*rinv, q.z*rinv, q.w*rinv};
        ((float4*)img_n)[(size_t)i * D4 + tid] = n;
    }
}

// ---- K2: finalize BN stats (inline, redundant per block) + normalize cap -> capn
//      capn keeps the SAME [b][t][d] layout (no transpose needed).
__global__ __launch_bounds__(256) void k_prep(const float* __restrict__ cap,
                                              const float* __restrict__ ps,
                                              const float* __restrict__ pss,
                                              float* __restrict__ capn) {
    int bx = blockIdx.x, tid = threadIdx.x;
    const float4* ps4  = (const float4*)ps;
    const float4* pss4 = (const float4*)pss;
    float4 s = {0,0,0,0}, ss = {0,0,0,0};
#pragma unroll 8
    for (int rg = 0; rg < PRG; ++rg) {
        float4 a = ps4[(size_t)rg * D4 + tid];
        float4 b = pss4[(size_t)rg * D4 + tid];
        s.x += a.x; s.y += a.y; s.z += a.z; s.w += a.w;
        ss.x += b.x; ss.y += b.y; ss.z += b.z; ss.w += b.w;
    }
    const float inv = 1.f / 1920.f;
    float4 m = {s.x*inv, s.y*inv, s.z*inv, s.w*inv};
    float4 sc;
    sc.x = rsqrtf(ss.x*inv - m.x*m.x + EPSF);
    sc.y = rsqrtf(ss.y*inv - m.y*m.y + EPSF);
    sc.z = rsqrtf(ss.z*inv - m.z*m.z + EPSF);
    sc.w = rsqrtf(ss.w*inv - m.w*m.w + EPSF);
    const float4* cap4 = (const float4*)cap;
    float4* capn4 = (float4*)capn;
    int r0 = bx * ROWS2;
#pragma unroll 4
    for (int r = 0; r < ROWS2; ++r) {
        size_t off = (size_t)(r0 + r) * D4 + tid;
        float4 v = cap4[off];
        float4 o = {(v.x - m.x)*sc.x, (v.y - m.y)*sc.y,
                    (v.z - m.z)*sc.z, (v.w - m.w)*sc.w};
        capn4[off] = o;
    }
}

// ---- K3: FiLM GEMMs. Virtual rows 0..1023 = gamma d, 1024..2047 = beta d.
// Wave = 4 rows x 24 images; lane = k-slice (float4). acc[4][24] static-indexed.
__global__ __launch_bounds__(256) void k_film(const float* __restrict__ img_q,
                                              const float* __restrict__ Wg,
                                              const float* __restrict__ bg,
                                              const float* __restrict__ Wb,
                                              const float* __restrict__ bb,
                                              float* __restrict__ g1,
                                              float* __restrict__ be) {
    __shared__ float4 lq4[BI * 64];          // 48*64*16B = 48 KiB
    int tid = threadIdx.x;
    int wave = tid >> 6, lane = tid & 63;
    int gw = blockIdx.x * 4 + wave;          // 0..1023
    int rgrp = gw >> 1;                      // 0..511 -> rows rgrp*4..+3
    int ih = gw & 1;                         // image half: i = ih*24 + 0..23
    float acc[4][24];
#pragma unroll
    for (int r = 0; r < 4; ++r)
#pragma unroll
        for (int i = 0; i < 24; ++i) acc[r][i] = 0.f;

    const float4* q4g = (const float4*)img_q;
    for (int kc = 0; kc < 4; ++kc) {
        __syncthreads();
        for (int idx = tid; idx < BI * 64; idx += 256) {
            int i = idx >> 6, kk = idx & 63;
            lq4[idx] = q4g[(size_t)i * D4 + kc * 64 + kk];
        }
        __syncthreads();
        float4 wv[4];
#pragma unroll
        for (int r = 0; r < 4; ++r) {
            int row = rgrp * 4 + r;
            const float4* W4 = (const float4*)((row & 1024) ? Wb : Wg);
            int d = row & 1023;
            wv[r] = W4[(size_t)d * D4 + kc * 64 + lane];
        }
#pragma unroll
        for (int i = 0; i < 24; ++i) {
            float4 q = lq4[(ih * 24 + i) * 64 + lane];
#pragma unroll
            for (int r = 0; r < 4; ++r) {
                acc[r][i] = fmaf(wv[r].x, q.x, acc[r][i]);
                acc[r][i] = fmaf(wv[r].y, q.y, acc[r][i]);
                acc[r][i] = fmaf(wv[r].z, q.z, acc[r][i]);
                acc[r][i] = fmaf(wv[r].w, q.w, acc[r][i]);
            }
        }
    }
#pragma unroll
    for (int r = 0; r < 4; ++r)
#pragma unroll
        for (int i = 0; i < 24; ++i) {
            float v = acc[r][i];
#pragma unroll
            for (int off = 32; off; off >>= 1) v += __shfl_xor(v, off, 64);
            acc[r][i] = v;
        }
#pragma unroll
    for (int r = 0; r < 4; ++r) {
        int row = rgrp * 4 + r;
        int isbeta = (row >> 10) & 1;
        int d = row & 1023;
        float badd = isbeta ? bb[d] : (bg[d] + 1.f);   // store 1+gamma
        float* outp = isbeta ? be : g1;
#pragma unroll
        for (int i = 0; i < 24; ++i) {
            if (lane == ((r * 24 + i) & 63))
                outp[(size_t)(ih * 24 + i) * D + d] = acc[r][i] + badd;
        }
    }
}

// ---- K4: fused Fovea + l2norm + cosine. Thread owns a d-quad; block = (b, 2 images).
// No max-subtraction: |x| <= ~11 so exp(x) is safe in f32.
// max_t(softmax_t * x_t) == max_t(x_t * e^{x_t}) / sum_t e^{x_t}
__global__ __launch_bounds__(256) void k_fovea(const float* __restrict__ capn,
                                               const float* __restrict__ g1,
                                               const float* __restrict__ be,
                                               const float* __restrict__ img_n,
                                               float* __restrict__ out) {
    int blk = blockIdx.x;                // b-major: 24 consecutive blocks share capn[b]
    int b = blk / 24, ig = blk - b * 24;
    int i0 = ig * 2;
    int tid = threadIdx.x;
    const float4* capn4 = (const float4*)capn;
    float g[2][4], bt[2][4];
    {
        const float4* g14 = (const float4*)g1;
        const float4* be4 = (const float4*)be;
        float4 t0 = g14[(size_t)i0 * D4 + tid];
        float4 t1 = g14[(size_t)(i0 + 1) * D4 + tid];
        g[0][0]=t0.x; g[0][1]=t0.y; g[0][2]=t0.z; g[0][3]=t0.w;
        g[1][0]=t1.x; g[1][1]=t1.y; g[1][2]=t1.z; g[1][3]=t1.w;
        float4 u0 = be4[(size_t)i0 * D4 + tid];
        float4 u1 = be4[(size_t)(i0 + 1) * D4 + tid];
        bt[0][0]=u0.x; bt[0][1]=u0.y; bt[0][2]=u0.z; bt[0][3]=u0.w;
        bt[1][0]=u1.x; bt[1][1]=u1.y; bt[1][2]=u1.z; bt[1][3]=u1.w;
    }
    float s[2][4], vm[2][4];
#pragma unroll
    for (int u = 0; u < 2; ++u)
#pragma unroll
        for (int c = 0; c < 4; ++c) { s[u][c] = 0.f; vm[u][c] = -INFINITY; }

#pragma unroll 8
    for (int t = 0; t < TT; ++t) {
        float4 c4 = capn4[((size_t)b * TT + t) * D4 + tid];
        float cc[4] = {c4.x, c4.y, c4.z, c4.w};
#pragma unroll
        for (int u = 0; u < 2; ++u)
#pragma unroll
            for (int c = 0; c < 4; ++c) {
                float x = fmaf(cc[c], g[u][c], bt[u][c]);
                float e = __expf(x);
                s[u][c] += e;
                vm[u][c] = fmaxf(vm[u][c], e * x);
            }
    }
    const float4* in4 = (const float4*)img_n;
    float dred[2], sred[2];
#pragma unroll
    for (int u = 0; u < 2; ++u) {
        float4 nn = in4[(size_t)(i0 + u) * D4 + tid];
        float n[4] = {nn.x, nn.y, nn.z, nn.w};
        float dd = 0.f, sq = 0.f;
#pragma unroll
        for (int c = 0; c < 4; ++c) {
            float v = vm[u][c] / s[u][c];
            sq += v * v;
            dd += v * n[c];
        }
        dred[u] = dd; sred[u] = sq;
    }
#pragma unroll
    for (int off = 32; off; off >>= 1) {
        dred[0] += __shfl_xor(dred[0], off, 64);
        dred[1] += __shfl_xor(dred[1], off, 64);
        sred[0] += __shfl_xor(sred[0], off, 64);
        sred[1] += __shfl_xor(sred[1], off, 64);
    }
    __shared__ float red[4][4];
    int wave = tid >> 6, lane = tid & 63;
    if (lane == 0) {
        red[0][wave] = dred[0]; red[1][wave] = sred[0];
        red[2][wave] = dred[1]; red[3][wave] = sred[1];
    }
    __syncthreads();
    if (tid == 0) {
        float d0 = red[0][0] + red[0][1] + red[0][2] + red[0][3];
        float s0 = red[1][0] + red[1][1] + red[1][2] + red[1][3];
        float d1 = red[2][0] + red[2][1] + red[2][2] + red[2][3];
        float s1 = red[3][0] + red[3][1] + red[3][2] + red[3][3];
        out[(size_t)i0 * BC + b]       = d0 / sqrtf(s0);
        out[(size_t)(i0 + 1) * BC + b] = d1 / sqrtf(s1);
    }
}

extern "C" void kernel_launch(void* const* d_in, const int* in_sizes, int n_in,
                              void* d_out, int out_size, void* d_ws, size_t ws_size,
                              hipStream_t stream) {
    const float* img = (const float*)d_in[0];
    const float* cap = (const float*)d_in[1];
    // d_in[2] = lens (unused)
    const float* Wg  = (const float*)d_in[3];
    const float* bg  = (const float*)d_in[4];
    const float* Wb  = (const float*)d_in[5];
    const float* bb  = (const float*)d_in[6];
    float* out = (float*)d_out;

    float* ws    = (float*)d_ws;
    float* ps    = ws;                     // 40*1024
    float* pss   = ps    + PRG * D;        // 40*1024
    float* img_q = pss   + PRG * D;        // 48*1024
    float* img_n = img_q + BI * D;         // 48*1024
    float* g1    = img_n + BI * D;         // 48*1024
    float* be    = g1    + BI * D;         // 48*1024
    float* capn  = be    + BI * D;         // 1920*1024

    hipLaunchKernelGGL(k_stats, dim3(PRG + BI), dim3(256), 0, stream,
                       cap, img, ps, pss, img_q, img_n);
    hipLaunchKernelGGL(k_prep,  dim3(NBLK2),    dim3(256), 0, stream,
                       cap, ps, pss, capn);
    hipLaunchKernelGGL(k_film,  dim3(256),      dim3(256), 0, stream,
                       img_q, Wg, bg, Wb, bb, g1, be);
    hipLaunchKernelGGL(k_fovea, dim3(BI * 24),  dim3(256), 0, stream,
                       capn, g1, be, img_n, out);
}

// Round 3
// 72.566 us; speedup vs baseline: 1.2053x; 1.2053x over previous
//
#include <hip/hip_runtime.h>
#include <math.h>

#define D     1024
#define D4    256     // D/4
#define BI    48
#define BC    48
#define RR    36
#define TT    40
#define EPSF  1e-5f
#define PRG   128     // cap-stat row groups
#define CROWS 15      // rows per group (128*15 = 1920)

// ---- K1: cap BN partial sums (blocks 0..127) + img_q/img_n (blocks 128..175)
__global__ __launch_bounds__(256) void k_stats(const float* __restrict__ cap,
                                               const float* __restrict__ img,
                                               float* __restrict__ ps,
                                               float* __restrict__ pss,
                                               float* __restrict__ img_q,
                                               float* __restrict__ img_n) {
    __shared__ float sw[4];
    int bx = blockIdx.x, tid = threadIdx.x;
    if (bx < PRG) {
        const float4* cap4 = (const float4*)cap;
        float4 s = {0,0,0,0}, ss = {0,0,0,0};
        int r0 = bx * CROWS;
#pragma unroll
        for (int r = 0; r < CROWS; ++r) {
            float4 v = cap4[(size_t)(r0 + r) * D4 + tid];
            s.x += v.x; s.y += v.y; s.z += v.z; s.w += v.w;
            ss.x += v.x*v.x; ss.y += v.y*v.y; ss.z += v.z*v.z; ss.w += v.w*v.w;
        }
        ((float4*)ps)[(size_t)bx * D4 + tid]  = s;
        ((float4*)pss)[(size_t)bx * D4 + tid] = ss;
    } else {
        int i = bx - PRG;
        const float4* img4 = (const float4*)img;
        float4 s = {0,0,0,0};
#pragma unroll
        for (int r = 0; r < RR; ++r) {
            float4 v = img4[((size_t)i * RR + r) * D4 + tid];
            s.x += v.x; s.y += v.y; s.z += v.z; s.w += v.w;
        }
        const float inv = 1.f / 36.f;
        float4 q = {s.x*inv, s.y*inv, s.z*inv, s.w*inv};
        ((float4*)img_q)[(size_t)i * D4 + tid] = q;
        float ssq = q.x*q.x + q.y*q.y + q.z*q.z + q.w*q.w;
#pragma unroll
        for (int off = 32; off; off >>= 1) ssq += __shfl_xor(ssq, off, 64);
        if ((tid & 63) == 0) sw[tid >> 6] = ssq;
        __syncthreads();
        float rinv = rsqrtf(sw[0] + sw[1] + sw[2] + sw[3]);
        float4 n = {q.x*rinv, q.y*rinv, q.z*rinv, q.w*rinv};
        ((float4*)img_n)[(size_t)i * D4 + tid] = n;
    }
}

// ---- K2: FiLM GEMMs (blocks 0..255) + BN finalize (blocks 256..263)
__global__ __launch_bounds__(256) void k_film(const float* __restrict__ img_q,
                                              const float* __restrict__ Wg,
                                              const float* __restrict__ bg,
                                              const float* __restrict__ Wb,
                                              const float* __restrict__ bb,
                                              const float* __restrict__ ps,
                                              const float* __restrict__ pss,
                                              float* __restrict__ g1,
                                              float* __restrict__ be,
                                              float* __restrict__ mean,
                                              float* __restrict__ scale) {
    __shared__ float4 lq4[BI * 64];          // 48 KiB (also scratch for finalize)
    int tid = threadIdx.x;

    if (blockIdx.x >= 256) {                 // ---- BN finalize: 8 blocks
        int bx2 = blockIdx.x - 256;          // 0..7
        int c32 = tid & 31;
        int col = bx2 * 32 + c32;            // float4 column 0..255
        int rs  = tid >> 5;                  // 0..7 row-subsets
        const float4* ps4  = (const float4*)ps;
        const float4* pss4 = (const float4*)pss;
        float4 s = {0,0,0,0}, q = {0,0,0,0};
#pragma unroll
        for (int gi = 0; gi < PRG / 8; ++gi) {
            int rg = rs * (PRG / 8) + gi;
            float4 a  = ps4[(size_t)rg * D4 + col];
            float4 b2 = pss4[(size_t)rg * D4 + col];
            s.x += a.x;  s.y += a.y;  s.z += a.z;  s.w += a.w;
            q.x += b2.x; q.y += b2.y; q.z += b2.z; q.w += b2.w;
        }
        float4* red = lq4;
        red[rs * 32 + c32]       = s;
        red[256 + rs * 32 + c32] = q;
        __syncthreads();
        if (rs == 0) {
            float4 S = {0,0,0,0}, Q = {0,0,0,0};
#pragma unroll
            for (int r2 = 0; r2 < 8; ++r2) {
                float4 a  = red[r2 * 32 + c32];
                float4 b2 = red[256 + r2 * 32 + c32];
                S.x += a.x;  S.y += a.y;  S.z += a.z;  S.w += a.w;
                Q.x += b2.x; Q.y += b2.y; Q.z += b2.z; Q.w += b2.w;
            }
            const float inv = 1.f / 1920.f;
            float4 M = {S.x*inv, S.y*inv, S.z*inv, S.w*inv};
            float4 SC;
            SC.x = rsqrtf(Q.x*inv - M.x*M.x + EPSF);
            SC.y = rsqrtf(Q.y*inv - M.y*M.y + EPSF);
            SC.z = rsqrtf(Q.z*inv - M.z*M.z + EPSF);
            SC.w = rsqrtf(Q.w*inv - M.w*M.w + EPSF);
            ((float4*)mean)[col]  = M;
            ((float4*)scale)[col] = SC;
        }
        return;
    }

    // ---- FiLM GEMM path (identical structure to R2, which validated)
    int wave = tid >> 6, lane = tid & 63;
    int gw = blockIdx.x * 4 + wave;          // 0..1023
    int rgrp = gw >> 1;                      // rows rgrp*4..+3 (0..511)
    int ih = gw & 1;                         // image half
    float acc[4][24];
#pragma unroll
    for (int r = 0; r < 4; ++r)
#pragma unroll
        for (int i = 0; i < 24; ++i) acc[r][i] = 0.f;

    const float4* q4g = (const float4*)img_q;
    for (int kc = 0; kc < 4; ++kc) {
        __syncthreads();
        for (int idx = tid; idx < BI * 64; idx += 256) {
            int i = idx >> 6, kk = idx & 63;
            lq4[idx] = q4g[(size_t)i * D4 + kc * 64 + kk];
        }
        __syncthreads();
        float4 wv[4];
#pragma unroll
        for (int r = 0; r < 4; ++r) {
            int row = rgrp * 4 + r;
            const float4* W4 = (const float4*)((row & 1024) ? Wb : Wg);
            int d = row & 1023;
            wv[r] = W4[(size_t)d * D4 + kc * 64 + lane];
        }
#pragma unroll
        for (int i = 0; i < 24; ++i) {
            float4 q = lq4[(ih * 24 + i) * 64 + lane];
#pragma unroll
            for (int r = 0; r < 4; ++r) {
                acc[r][i] = fmaf(wv[r].x, q.x, acc[r][i]);
                acc[r][i] = fmaf(wv[r].y, q.y, acc[r][i]);
                acc[r][i] = fmaf(wv[r].z, q.z, acc[r][i]);
                acc[r][i] = fmaf(wv[r].w, q.w, acc[r][i]);
            }
        }
    }
#pragma unroll
    for (int r = 0; r < 4; ++r)
#pragma unroll
        for (int i = 0; i < 24; ++i) {
            float v = acc[r][i];
#pragma unroll
            for (int off = 32; off; off >>= 1) v += __shfl_xor(v, off, 64);
            acc[r][i] = v;
        }
#pragma unroll
    for (int r = 0; r < 4; ++r) {
        int row = rgrp * 4 + r;
        int isbeta = (row >> 10) & 1;
        int d = row & 1023;
        float badd = isbeta ? bb[d] : (bg[d] + 1.f);   // store 1+gamma
        float* outp = isbeta ? be : g1;
#pragma unroll
        for (int i = 0; i < 24; ++i) {
            if (lane == ((r * 24 + i) & 63))
                outp[(size_t)(ih * 24 + i) * D + d] = acc[r][i] + badd;
        }
    }
}

// ---- K3: fused BN-normalize + Fovea + l2norm + cosine.
// Block = (b, 4 images). XCD-bijective swizzle keeps same-b blocks on one XCD.
// No max-subtraction (|x| small); max_t(softmax*x) = max_t(x e^x)/sum e^x.
__global__ __launch_bounds__(256) void k_fovea(const float* __restrict__ cap,
                                               const float* __restrict__ mean,
                                               const float* __restrict__ scale,
                                               const float* __restrict__ g1,
                                               const float* __restrict__ be,
                                               const float* __restrict__ img_n,
                                               float* __restrict__ out) {
    int j = blockIdx.x;                      // 576 = 48 b * 12 ig
    int wg = (j & 7) * 72 + (j >> 3);        // bijective XCD swizzle (576 % 8 == 0)
    int b = wg / 12, ig = wg - b * 12;
    int i0 = ig * 4;
    int tid = threadIdx.x;

    const float4* cap4 = (const float4*)cap;
    float4 m4  = ((const float4*)mean)[tid];
    float4 sc4 = ((const float4*)scale)[tid];
    float mm[4] = {m4.x, m4.y, m4.z, m4.w};
    float sc[4] = {sc4.x, sc4.y, sc4.z, sc4.w};

    float g[4][4], bt[4][4];
#pragma unroll
    for (int u = 0; u < 4; ++u) {
        float4 t0 = ((const float4*)g1)[(size_t)(i0 + u) * D4 + tid];
        g[u][0] = t0.x; g[u][1] = t0.y; g[u][2] = t0.z; g[u][3] = t0.w;
        float4 u0 = ((const float4*)be)[(size_t)(i0 + u) * D4 + tid];
        bt[u][0] = u0.x; bt[u][1] = u0.y; bt[u][2] = u0.z; bt[u][3] = u0.w;
    }
    float se[4][4], vm[4][4];
#pragma unroll
    for (int u = 0; u < 4; ++u)
#pragma unroll
        for (int c = 0; c < 4; ++c) { se[u][c] = 0.f; vm[u][c] = -INFINITY; }

#pragma unroll 2
    for (int t = 0; t < TT; ++t) {
        float4 c4 = cap4[((size_t)b * TT + t) * D4 + tid];
        float cc[4];
        cc[0] = (c4.x - mm[0]) * sc[0];
        cc[1] = (c4.y - mm[1]) * sc[1];
        cc[2] = (c4.z - mm[2]) * sc[2];
        cc[3] = (c4.w - mm[3]) * sc[3];
#pragma unroll
        for (int u = 0; u < 4; ++u)
#pragma unroll
            for (int c = 0; c < 4; ++c) {
                float x = fmaf(cc[c], g[u][c], bt[u][c]);
                float e = __expf(x);
                se[u][c] += e;
                vm[u][c] = fmaxf(vm[u][c], e * x);
            }
    }
    float dd[4], sq[4];
#pragma unroll
    for (int u = 0; u < 4; ++u) {
        float4 nn = ((const float4*)img_n)[(size_t)(i0 + u) * D4 + tid];
        float n[4] = {nn.x, nn.y, nn.z, nn.w};
        float d2 = 0.f, q2 = 0.f;
#pragma unroll
        for (int c = 0; c < 4; ++c) {
            float v = vm[u][c] / se[u][c];
            q2 += v * v;
            d2 += v * n[c];
        }
        dd[u] = d2; sq[u] = q2;
    }
#pragma unroll
    for (int off = 32; off; off >>= 1) {
#pragma unroll
        for (int u = 0; u < 4; ++u) {
            dd[u] += __shfl_xor(dd[u], off, 64);
            sq[u] += __shfl_xor(sq[u], off, 64);
        }
    }
    __shared__ float rd[4][4], rq[4][4];     // [u][wave]
    int wave = tid >> 6, lane = tid & 63;
    if (lane == 0) {
#pragma unroll
        for (int u = 0; u < 4; ++u) { rd[u][wave] = dd[u]; rq[u][wave] = sq[u]; }
    }
    __syncthreads();
    if (tid < 4) {
        float td = rd[tid][0] + rd[tid][1] + rd[tid][2] + rd[tid][3];
        float ts = rq[tid][0] + rq[tid][1] + rq[tid][2] + rq[tid][3];
        out[(size_t)(i0 + tid) * BC + b] = td / sqrtf(ts);
    }
}

extern "C" void kernel_launch(void* const* d_in, const int* in_sizes, int n_in,
                              void* d_out, int out_size, void* d_ws, size_t ws_size,
                              hipStream_t stream) {
    const float* img = (const float*)d_in[0];
    const float* cap = (const float*)d_in[1];
    // d_in[2] = lens (unused)
    const float* Wg  = (const float*)d_in[3];
    const float* bg  = (const float*)d_in[4];
    const float* Wb  = (const float*)d_in[5];
    const float* bb  = (const float*)d_in[6];
    float* out = (float*)d_out;

    float* ws    = (float*)d_ws;
    float* ps    = ws;                     // 128*1024
    float* pss   = ps    + PRG * D;        // 128*1024
    float* img_q = pss   + PRG * D;        // 48*1024
    float* img_n = img_q + BI * D;         // 48*1024
    float* g1    = img_n + BI * D;         // 48*1024
    float* be    = g1    + BI * D;         // 48*1024
    float* mean  = be    + BI * D;         // 1024
    float* scale = mean  + D;              // 1024

    hipLaunchKernelGGL(k_stats, dim3(PRG + BI), dim3(256), 0, stream,
                       cap, img, ps, pss, img_q, img_n);
    hipLaunchKernelGGL(k_film,  dim3(264),      dim3(256), 0, stream,
                       img_q, Wg, bg, Wb, bb, ps, pss, g1, be, mean, scale);
    hipLaunchKernelGGL(k_fovea, dim3(576),      dim3(256), 0, stream,
                       cap, mean, scale, g1, be, img_n, out);
}

// Round 4
// 62.995 us; speedup vs baseline: 1.3884x; 1.1519x over previous
//
#include <hip/hip_runtime.h>
#include <math.h>

#define D     1024
#define D4    256     // D/4
#define BI    48
#define BC    48
#define RR    36
#define TT    40
#define EPSF  1e-5f
#define PRG   128     // cap-stat row groups
#define CROWS 15      // rows per group (128*15 = 1920)

// ---- K1: cap BN partial sums (blocks 0..127) + img_q/img_n (blocks 128..175)
__global__ __launch_bounds__(256) void k_stats(const float* __restrict__ cap,
                                               const float* __restrict__ img,
                                               float* __restrict__ ps,
                                               float* __restrict__ pss,
                                               float* __restrict__ img_q,
                                               float* __restrict__ img_n) {
    __shared__ float sw[4];
    int bx = blockIdx.x, tid = threadIdx.x;
    if (bx < PRG) {
        const float4* cap4 = (const float4*)cap;
        float4 s = {0,0,0,0}, ss = {0,0,0,0};
        int r0 = bx * CROWS;
#pragma unroll
        for (int r = 0; r < CROWS; ++r) {
            float4 v = cap4[(size_t)(r0 + r) * D4 + tid];
            s.x += v.x; s.y += v.y; s.z += v.z; s.w += v.w;
            ss.x += v.x*v.x; ss.y += v.y*v.y; ss.z += v.z*v.z; ss.w += v.w*v.w;
        }
        ((float4*)ps)[(size_t)bx * D4 + tid]  = s;
        ((float4*)pss)[(size_t)bx * D4 + tid] = ss;
    } else {
        int i = bx - PRG;
        const float4* img4 = (const float4*)img;
        float4 s = {0,0,0,0};
#pragma unroll
        for (int r = 0; r < RR; ++r) {
            float4 v = img4[((size_t)i * RR + r) * D4 + tid];
            s.x += v.x; s.y += v.y; s.z += v.z; s.w += v.w;
        }
        const float inv = 1.f / 36.f;
        float4 q = {s.x*inv, s.y*inv, s.z*inv, s.w*inv};
        ((float4*)img_q)[(size_t)i * D4 + tid] = q;
        float ssq = q.x*q.x + q.y*q.y + q.z*q.z + q.w*q.w;
#pragma unroll
        for (int off = 32; off; off >>= 1) ssq += __shfl_xor(ssq, off, 64);
        if ((tid & 63) == 0) sw[tid >> 6] = ssq;
        __syncthreads();
        float rinv = rsqrtf(sw[0] + sw[1] + sw[2] + sw[3]);
        float4 n = {q.x*rinv, q.y*rinv, q.z*rinv, q.w*rinv};
        ((float4*)img_n)[(size_t)i * D4 + tid] = n;
    }
}

// ---- K2: FiLM GEMMs (blocks 0..511: wave = 1 virtual row x 48 images)
//          + BN finalize (blocks 512..519)
__global__ __launch_bounds__(256) void k_film(const float* __restrict__ img_q,
                                              const float* __restrict__ Wg,
                                              const float* __restrict__ bg,
                                              const float* __restrict__ Wb,
                                              const float* __restrict__ bb,
                                              const float* __restrict__ ps,
                                              const float* __restrict__ pss,
                                              float* __restrict__ g1,
                                              float* __restrict__ be,
                                              float* __restrict__ mean,
                                              float* __restrict__ scale) {
    __shared__ float4 lq4[BI * 64];          // 48 KiB (scratch for finalize too)
    int tid = threadIdx.x;

    if (blockIdx.x >= 512) {                 // ---- BN finalize: 8 blocks
        int bx2 = blockIdx.x - 512;          // 0..7
        int c32 = tid & 31;
        int col = bx2 * 32 + c32;            // float4 column 0..255
        int rs  = tid >> 5;                  // 0..7 row-subsets
        const float4* ps4  = (const float4*)ps;
        const float4* pss4 = (const float4*)pss;
        float4 s = {0,0,0,0}, q = {0,0,0,0};
#pragma unroll
        for (int gi = 0; gi < PRG / 8; ++gi) {
            int rg = rs * (PRG / 8) + gi;
            float4 a  = ps4[(size_t)rg * D4 + col];
            float4 b2 = pss4[(size_t)rg * D4 + col];
            s.x += a.x;  s.y += a.y;  s.z += a.z;  s.w += a.w;
            q.x += b2.x; q.y += b2.y; q.z += b2.z; q.w += b2.w;
        }
        float4* red = lq4;
        red[rs * 32 + c32]       = s;
        red[256 + rs * 32 + c32] = q;
        __syncthreads();
        if (rs == 0) {
            float4 S = {0,0,0,0}, Q = {0,0,0,0};
#pragma unroll
            for (int r2 = 0; r2 < 8; ++r2) {
                float4 a  = red[r2 * 32 + c32];
                float4 b2 = red[256 + r2 * 32 + c32];
                S.x += a.x;  S.y += a.y;  S.z += a.z;  S.w += a.w;
                Q.x += b2.x; Q.y += b2.y; Q.z += b2.z; Q.w += b2.w;
            }
            const float inv = 1.f / 1920.f;
            float4 M = {S.x*inv, S.y*inv, S.z*inv, S.w*inv};
            float4 SC;
            SC.x = rsqrtf(Q.x*inv - M.x*M.x + EPSF);
            SC.y = rsqrtf(Q.y*inv - M.y*M.y + EPSF);
            SC.z = rsqrtf(Q.z*inv - M.z*M.z + EPSF);
            SC.w = rsqrtf(Q.w*inv - M.w*M.w + EPSF);
            ((float4*)mean)[col]  = M;
            ((float4*)scale)[col] = SC;
        }
        return;
    }

    // ---- FiLM GEMM: wave = one virtual row (0..2047), all 48 images
    int wave = tid >> 6, lane = tid & 63;
    int row = blockIdx.x * 4 + wave;         // 0..2047
    int isbeta = row >> 10;
    int d = row & 1023;
    const float4* W4 = (const float4*)(isbeta ? Wb : Wg);

    float acc[BI];
#pragma unroll
    for (int i = 0; i < BI; ++i) acc[i] = 0.f;

    const float4* q4g = (const float4*)img_q;
    for (int kc = 0; kc < 4; ++kc) {
        __syncthreads();
        for (int idx = tid; idx < BI * 64; idx += 256) {
            int i = idx >> 6, kk = idx & 63;
            lq4[idx] = q4g[(size_t)i * D4 + kc * 64 + kk];
        }
        __syncthreads();
        float4 wv = W4[(size_t)d * D4 + kc * 64 + lane];
#pragma unroll
        for (int i = 0; i < BI; ++i) {
            float4 q = lq4[i * 64 + lane];
            acc[i] = fmaf(wv.x, q.x, acc[i]);
            acc[i] = fmaf(wv.y, q.y, acc[i]);
            acc[i] = fmaf(wv.z, q.z, acc[i]);
            acc[i] = fmaf(wv.w, q.w, acc[i]);
        }
    }
    // reduce each acc[i] across the wave; lane i keeps output for image i
    float myval = 0.f;
#pragma unroll
    for (int i = 0; i < BI; ++i) {
        float v = acc[i];
#pragma unroll
        for (int off = 32; off; off >>= 1) v += __shfl_xor(v, off, 64);
        if (lane == i) myval = v;
    }
    if (lane < BI) {
        float badd = isbeta ? bb[d] : (bg[d] + 1.f);   // store 1+gamma
        float* outp = isbeta ? be : g1;
        outp[(size_t)lane * D + d] = myval + badd;
    }
}

// ---- K3: fused BN-normalize + Fovea + l2norm + cosine.
// Block = (b, 4 images). XCD-bijective swizzle keeps same-b blocks on one XCD.
// No max-subtraction (|x| small); max_t(softmax*x) = max_t(x e^x)/sum e^x.
__global__ __launch_bounds__(256) void k_fovea(const float* __restrict__ cap,
                                               const float* __restrict__ mean,
                                               const float* __restrict__ scale,
                                               const float* __restrict__ g1,
                                               const float* __restrict__ be,
                                               const float* __restrict__ img_n,
                                               float* __restrict__ out) {
    int j = blockIdx.x;                      // 576 = 48 b * 12 ig
    int wg = (j & 7) * 72 + (j >> 3);        // bijective XCD swizzle (576 % 8 == 0)
    int b = wg / 12, ig = wg - b * 12;
    int i0 = ig * 4;
    int tid = threadIdx.x;

    const float4* cap4 = (const float4*)cap;
    float4 m4  = ((const float4*)mean)[tid];
    float4 sc4 = ((const float4*)scale)[tid];
    float mm[4] = {m4.x, m4.y, m4.z, m4.w};
    float sc[4] = {sc4.x, sc4.y, sc4.z, sc4.w};

    float g[4][4], bt[4][4];
#pragma unroll
    for (int u = 0; u < 4; ++u) {
        float4 t0 = ((const float4*)g1)[(size_t)(i0 + u) * D4 + tid];
        g[u][0] = t0.x; g[u][1] = t0.y; g[u][2] = t0.z; g[u][3] = t0.w;
        float4 u0 = ((const float4*)be)[(size_t)(i0 + u) * D4 + tid];
        bt[u][0] = u0.x; bt[u][1] = u0.y; bt[u][2] = u0.z; bt[u][3] = u0.w;
    }
    float se[4][4], vm[4][4];
#pragma unroll
    for (int u = 0; u < 4; ++u)
#pragma unroll
        for (int c = 0; c < 4; ++c) { se[u][c] = 0.f; vm[u][c] = -INFINITY; }

#pragma unroll 2
    for (int t = 0; t < TT; ++t) {
        float4 c4 = cap4[((size_t)b * TT + t) * D4 + tid];
        float cc[4];
        cc[0] = (c4.x - mm[0]) * sc[0];
        cc[1] = (c4.y - mm[1]) * sc[1];
        cc[2] = (c4.z - mm[2]) * sc[2];
        cc[3] = (c4.w - mm[3]) * sc[3];
#pragma unroll
        for (int u = 0; u < 4; ++u)
#pragma unroll
            for (int c = 0; c < 4; ++c) {
                float x = fmaf(cc[c], g[u][c], bt[u][c]);
                float e = __expf(x);
                se[u][c] += e;
                vm[u][c] = fmaxf(vm[u][c], e * x);
            }
    }
    float dd[4], sq[4];
#pragma unroll
    for (int u = 0; u < 4; ++u) {
        float4 nn = ((const float4*)img_n)[(size_t)(i0 + u) * D4 + tid];
        float n[4] = {nn.x, nn.y, nn.z, nn.w};
        float d2 = 0.f, q2 = 0.f;
#pragma unroll
        for (int c = 0; c < 4; ++c) {
            float v = vm[u][c] / se[u][c];
            q2 += v * v;
            d2 += v * n[c];
        }
        dd[u] = d2; sq[u] = q2;
    }
#pragma unroll
    for (int off = 32; off; off >>= 1) {
#pragma unroll
        for (int u = 0; u < 4; ++u) {
            dd[u] += __shfl_xor(dd[u], off, 64);
            sq[u] += __shfl_xor(sq[u], off, 64);
        }
    }
    __shared__ float rd[4][4], rq[4][4];     // [u][wave]
    int wave = tid >> 6, lane = tid & 63;
    if (lane == 0) {
#pragma unroll
        for (int u = 0; u < 4; ++u) { rd[u][wave] = dd[u]; rq[u][wave] = sq[u]; }
    }
    __syncthreads();
    if (tid < 4) {
        float td = rd[tid][0] + rd[tid][1] + rd[tid][2] + rd[tid][3];
        float ts = rq[tid][0] + rq[tid][1] + rq[tid][2] + rq[tid][3];
        out[(size_t)(i0 + tid) * BC + b] = td / sqrtf(ts);
    }
}

extern "C" void kernel_launch(void* const* d_in, const int* in_sizes, int n_in,
                              void* d_out, int out_size, void* d_ws, size_t ws_size,
                              hipStream_t stream) {
    const float* img = (const float*)d_in[0];
    const float* cap = (const float*)d_in[1];
    // d_in[2] = lens (unused)
    const float* Wg  = (const float*)d_in[3];
    const float* bg  = (const float*)d_in[4];
    const float* Wb  = (const float*)d_in[5];
    const float* bb  = (const float*)d_in[6];
    float* out = (float*)d_out;

    float* ws    = (float*)d_ws;
    float* ps    = ws;                     // 128*1024
    float* pss   = ps    + PRG * D;        // 128*1024
    float* img_q = pss   + PRG * D;        // 48*1024
    float* img_n = img_q + BI * D;         // 48*1024
    float* g1    = img_n + BI * D;         // 48*1024
    float* be    = g1    + BI * D;         // 48*1024
    float* mean  = be    + BI * D;         // 1024
    float* scale = mean  + D;              // 1024

    hipLaunchKernelGGL(k_stats, dim3(PRG + BI), dim3(256), 0, stream,
                       cap, img, ps, pss, img_q, img_n);
    hipLaunchKernelGGL(k_film,  dim3(520),      dim3(256), 0, stream,
                       img_q, Wg, bg, Wb, bb, ps, pss, g1, be, mean, scale);
    hipLaunchKernelGGL(k_fovea, dim3(576),      dim3(256), 0, stream,
                       cap, mean, scale, g1, be, img_n, out);
}

// Round 5
// 54.487 us; speedup vs baseline: 1.6052x; 1.1561x over previous
//
#include <hip/hip_runtime.h>
#include <math.h>

#define D     1024
#define D4    256     // D/4
#define BI    48
#define BC    48
#define RR    36
#define TT    40
#define EPSF  1e-5f
#define PRG   128     // cap-stat row groups
#define CROWS 15      // rows per group (128*15 = 1920)
#define L2E   1.4426950408889634f

// ---- K1: cap BN partial sums (blocks 0..127) + img_q/img_n (blocks 128..175)
__global__ __launch_bounds__(256) void k_stats(const float* __restrict__ cap,
                                               const float* __restrict__ img,
                                               float* __restrict__ ps,
                                               float* __restrict__ pss,
                                               float* __restrict__ img_q,
                                               float* __restrict__ img_n) {
    __shared__ float sw[4];
    int bx = blockIdx.x, tid = threadIdx.x;
    if (bx < PRG) {
        const float4* cap4 = (const float4*)cap;
        float4 s = {0,0,0,0}, ss = {0,0,0,0};
        int r0 = bx * CROWS;
#pragma unroll
        for (int r = 0; r < CROWS; ++r) {
            float4 v = cap4[(size_t)(r0 + r) * D4 + tid];
            s.x += v.x; s.y += v.y; s.z += v.z; s.w += v.w;
            ss.x += v.x*v.x; ss.y += v.y*v.y; ss.z += v.z*v.z; ss.w += v.w*v.w;
        }
        ((float4*)ps)[(size_t)bx * D4 + tid]  = s;
        ((float4*)pss)[(size_t)bx * D4 + tid] = ss;
    } else {
        int i = bx - PRG;
        const float4* img4 = (const float4*)img;
        float4 s = {0,0,0,0};
#pragma unroll
        for (int r = 0; r < RR; ++r) {
            float4 v = img4[((size_t)i * RR + r) * D4 + tid];
            s.x += v.x; s.y += v.y; s.z += v.z; s.w += v.w;
        }
        const float inv = 1.f / 36.f;
        float4 q = {s.x*inv, s.y*inv, s.z*inv, s.w*inv};
        ((float4*)img_q)[(size_t)i * D4 + tid] = q;
        float ssq = q.x*q.x + q.y*q.y + q.z*q.z + q.w*q.w;
#pragma unroll
        for (int off = 32; off; off >>= 1) ssq += __shfl_xor(ssq, off, 64);
        if ((tid & 63) == 0) sw[tid >> 6] = ssq;
        __syncthreads();
        float rinv = rsqrtf(sw[0] + sw[1] + sw[2] + sw[3]);
        float4 n = {q.x*rinv, q.y*rinv, q.z*rinv, q.w*rinv};
        ((float4*)img_n)[(size_t)i * D4 + tid] = n;
    }
}

// ---- K2: FiLM GEMMs (blocks 0..511: wave = 1 virtual row x 48 images)
//          + BN finalize (blocks 512..519)
// Reduction tail via LDS transpose (pad 49) instead of 288 shuffles.
__global__ __launch_bounds__(256) void k_film(const float* __restrict__ img_q,
                                              const float* __restrict__ Wg,
                                              const float* __restrict__ bg,
                                              const float* __restrict__ Wb,
                                              const float* __restrict__ bb,
                                              const float* __restrict__ ps,
                                              const float* __restrict__ pss,
                                              float* __restrict__ g1,
                                              float* __restrict__ be,
                                              float* __restrict__ mean,
                                              float* __restrict__ scale) {
    __shared__ float smem[12544];            // 50176 B: lq4 (49152) / trbuf 4x3136
    float4* lq4 = (float4*)smem;
    int tid = threadIdx.x;

    if (blockIdx.x >= 512) {                 // ---- BN finalize: 8 blocks
        int bx2 = blockIdx.x - 512;          // 0..7
        int c32 = tid & 31;
        int col = bx2 * 32 + c32;            // float4 column 0..255
        int rs  = tid >> 5;                  // 0..7 row-subsets
        const float4* ps4  = (const float4*)ps;
        const float4* pss4 = (const float4*)pss;
        float4 s = {0,0,0,0}, q = {0,0,0,0};
#pragma unroll
        for (int gi = 0; gi < PRG / 8; ++gi) {
            int rg = rs * (PRG / 8) + gi;
            float4 a  = ps4[(size_t)rg * D4 + col];
            float4 b2 = pss4[(size_t)rg * D4 + col];
            s.x += a.x;  s.y += a.y;  s.z += a.z;  s.w += a.w;
            q.x += b2.x; q.y += b2.y; q.z += b2.z; q.w += b2.w;
        }
        float4* red = lq4;
        red[rs * 32 + c32]       = s;
        red[256 + rs * 32 + c32] = q;
        __syncthreads();
        if (rs == 0) {
            float4 S = {0,0,0,0}, Q = {0,0,0,0};
#pragma unroll
            for (int r2 = 0; r2 < 8; ++r2) {
                float4 a  = red[r2 * 32 + c32];
                float4 b2 = red[256 + r2 * 32 + c32];
                S.x += a.x;  S.y += a.y;  S.z += a.z;  S.w += a.w;
                Q.x += b2.x; Q.y += b2.y; Q.z += b2.z; Q.w += b2.w;
            }
            const float inv = 1.f / 1920.f;
            float4 M = {S.x*inv, S.y*inv, S.z*inv, S.w*inv};
            float4 SC;
            SC.x = rsqrtf(Q.x*inv - M.x*M.x + EPSF);
            SC.y = rsqrtf(Q.y*inv - M.y*M.y + EPSF);
            SC.z = rsqrtf(Q.z*inv - M.z*M.z + EPSF);
            SC.w = rsqrtf(Q.w*inv - M.w*M.w + EPSF);
            ((float4*)mean)[col]  = M;
            ((float4*)scale)[col] = SC;
        }
        return;
    }

    // ---- FiLM GEMM: wave = one virtual row (0..2047), all 48 images
    int wave = tid >> 6, lane = tid & 63;
    int row = blockIdx.x * 4 + wave;         // 0..2047
    int isbeta = row >> 10;
    int d = row & 1023;
    const float4* W4 = (const float4*)(isbeta ? Wb : Wg);

    float acc[BI];
#pragma unroll
    for (int i = 0; i < BI; ++i) acc[i] = 0.f;

    const float4* q4g = (const float4*)img_q;
    for (int kc = 0; kc < 4; ++kc) {
        __syncthreads();
        for (int idx = tid; idx < BI * 64; idx += 256) {
            int i = idx >> 6, kk = idx & 63;
            lq4[idx] = q4g[(size_t)i * D4 + kc * 64 + kk];
        }
        __syncthreads();
        float4 wv = W4[(size_t)d * D4 + kc * 64 + lane];
#pragma unroll
        for (int i = 0; i < BI; ++i) {
            float4 q = lq4[i * 64 + lane];
            acc[i] = fmaf(wv.x, q.x, acc[i]);
            acc[i] = fmaf(wv.y, q.y, acc[i]);
            acc[i] = fmaf(wv.z, q.z, acc[i]);
            acc[i] = fmaf(wv.w, q.w, acc[i]);
        }
    }
    // transpose-reduce: wave-private LDS region, stride 49 (conflict-free)
    __syncthreads();                         // all waves done reading lq4
    float* tr = smem + wave * 3136;          // 64*49 floats
#pragma unroll
    for (int i = 0; i < BI; ++i) tr[lane * 49 + i] = acc[i];
    float s0 = 0.f, s1 = 0.f, s2 = 0.f, s3 = 0.f;
#pragma unroll
    for (int l = 0; l < 64; l += 4) {
        s0 += tr[(l + 0) * 49 + lane];
        s1 += tr[(l + 1) * 49 + lane];
        s2 += tr[(l + 2) * 49 + lane];
        s3 += tr[(l + 3) * 49 + lane];
    }
    float sum = (s0 + s1) + (s2 + s3);
    if (lane < BI) {
        float badd = isbeta ? bb[d] : (bg[d] + 1.f);   // store 1+gamma
        float* outp = isbeta ? be : g1;
        outp[(size_t)lane * D + d] = sum + badd;
    }
}

// ---- K3: fused BN-normalize + Fovea + l2norm + cosine.
// log2e fold: y = x*log2e, e=2^y, vm=max(y*e), se=sum(e); vm/se is the true
// value scaled by log2e (positive const per (i,b)) -> cancels in l2norm.
__global__ __launch_bounds__(256) void k_fovea(const float* __restrict__ cap,
                                               const float* __restrict__ mean,
                                               const float* __restrict__ scale,
                                               const float* __restrict__ g1,
                                               const float* __restrict__ be,
                                               const float* __restrict__ img_n,
                                               float* __restrict__ out) {
    int j = blockIdx.x;                      // 576 = 48 b * 12 ig
    int wg = (j & 7) * 72 + (j >> 3);        // bijective XCD swizzle (576 % 8 == 0)
    int b = wg / 12, ig = wg - b * 12;
    int i0 = ig * 4;
    int tid = threadIdx.x;

    const float4* cap4 = (const float4*)cap;
    float4 m4  = ((const float4*)mean)[tid];
    float4 sc4 = ((const float4*)scale)[tid];
    float mm[4] = {m4.x, m4.y, m4.z, m4.w};
    float sc[4] = {sc4.x, sc4.y, sc4.z, sc4.w};

    // G2 = g*sc*L2E ; B2 = (bt - g*sc*m)*L2E
    float G2[4][4], B2[4][4];
#pragma unroll
    for (int u = 0; u < 4; ++u) {
        float4 t0 = ((const float4*)g1)[(size_t)(i0 + u) * D4 + tid];
        float4 u0 = ((const float4*)be)[(size_t)(i0 + u) * D4 + tid];
        float gg[4] = {t0.x, t0.y, t0.z, t0.w};
        float bt[4] = {u0.x, u0.y, u0.z, u0.w};
#pragma unroll
        for (int c = 0; c < 4; ++c) {
            float t = gg[c] * sc[c];
            G2[u][c] = t * L2E;
            B2[u][c] = fmaf(-t, mm[c], bt[c]) * L2E;
        }
    }
    float se[4][4], vm[4][4];
#pragma unroll
    for (int u = 0; u < 4; ++u)
#pragma unroll
        for (int c = 0; c < 4; ++c) { se[u][c] = 0.f; vm[u][c] = -INFINITY; }

#pragma unroll 2
    for (int t = 0; t < TT; ++t) {
        float4 c4 = cap4[((size_t)b * TT + t) * D4 + tid];
        float cc[4] = {c4.x, c4.y, c4.z, c4.w};
#pragma unroll
        for (int u = 0; u < 4; ++u)
#pragma unroll
            for (int c = 0; c < 4; ++c) {
                float y = fmaf(cc[c], G2[u][c], B2[u][c]);
                float e = __builtin_amdgcn_exp2f(y);
                se[u][c] += e;
                vm[u][c] = fmaxf(vm[u][c], y * e);
            }
    }
    float dd[4], sq[4];
#pragma unroll
    for (int u = 0; u < 4; ++u) {
        float4 nn = ((const float4*)img_n)[(size_t)(i0 + u) * D4 + tid];
        float n[4] = {nn.x, nn.y, nn.z, nn.w};
        float d2 = 0.f, q2 = 0.f;
#pragma unroll
        for (int c = 0; c < 4; ++c) {
            float v = vm[u][c] / se[u][c];
            q2 += v * v;
            d2 += v * n[c];
        }
        dd[u] = d2; sq[u] = q2;
    }
#pragma unroll
    for (int off = 32; off; off >>= 1) {
#pragma unroll
        for (int u = 0; u < 4; ++u) {
            dd[u] += __shfl_xor(dd[u], off, 64);
            sq[u] += __shfl_xor(sq[u], off, 64);
        }
    }
    __shared__ float rd[4][4], rq[4][4];     // [u][wave]
    int wave = tid >> 6, lane = tid & 63;
    if (lane == 0) {
#pragma unroll
        for (int u = 0; u < 4; ++u) { rd[u][wave] = dd[u]; rq[u][wave] = sq[u]; }
    }
    __syncthreads();
    if (tid < 4) {
        float td = rd[tid][0] + rd[tid][1] + rd[tid][2] + rd[tid][3];
        float ts = rq[tid][0] + rq[tid][1] + rq[tid][2] + rq[tid][3];
        out[(size_t)(i0 + tid) * BC + b] = td / sqrtf(ts);
    }
}

extern "C" void kernel_launch(void* const* d_in, const int* in_sizes, int n_in,
                              void* d_out, int out_size, void* d_ws, size_t ws_size,
                              hipStream_t stream) {
    const float* img = (const float*)d_in[0];
    const float* cap = (const float*)d_in[1];
    // d_in[2] = lens (unused)
    const float* Wg  = (const float*)d_in[3];
    const float* bg  = (const float*)d_in[4];
    const float* Wb  = (const float*)d_in[5];
    const float* bb  = (const float*)d_in[6];
    float* out = (float*)d_out;

    float* ws    = (float*)d_ws;
    float* ps    = ws;                     // 128*1024
    float* pss   = ps    + PRG * D;        // 128*1024
    float* img_q = pss   + PRG * D;        // 48*1024
    float* img_n = img_q + BI * D;         // 48*1024
    float* g1    = img_n + BI * D;         // 48*1024
    float* be    = g1    + BI * D;         // 48*1024
    float* mean  = be    + BI * D;         // 1024
    float* scale = mean  + D;              // 1024

    hipLaunchKernelGGL(k_stats, dim3(PRG + BI), dim3(256), 0, stream,
                       cap, img, ps, pss, img_q, img_n);
    hipLaunchKernelGGL(k_film,  dim3(520),      dim3(256), 0, stream,
                       img_q, Wg, bg, Wb, bb, ps, pss, g1, be, mean, scale);
    hipLaunchKernelGGL(k_fovea, dim3(576),      dim3(256), 0, stream,
                       cap, mean, scale, g1, be, img_n, out);
}